// Round 6
// baseline (79.676 us; speedup 1.0000x reference)
//
#include <hip/hip_runtime.h>
#include <math.h>

#define NB 36
#define W 640
#define H 640
#define NSAMP 64
#define FIX_SCALE 8388608.0f    // 2^23: round total 640*2^23 needs u64 carry,
#define INV_FIX (1.0f/8388608.0f)  // but a 256-px round fits u32 (2^31).
#define CNT_SHIFT 44            // sample-bin sum < 640*640*2^23 = 2^41.7 < 2^44
#define AMB 1e-6

// Exact f64 golden chain (validated: absmax==0 in rounds 3-5).
__device__ __forceinline__ int bin_slow(int x, int y, double cxd, double cyd) {
    const double PI_D    = 3.141592653589793;
    const double TWOPI_D = 6.283185307179586;
    double t  = (atan2((double)y - cyd, (double)x - cxd) + PI_D) / TWOPI_D;
    double bd = t * 36.0;
    int k = (int)bd;
    k = k < 0 ? 0 : k;
    return k > NB - 1 ? NB - 1 : k;
}

// zero histogram + build cot table: tbl[m] = cot((m-18)*pi/18)
__global__ void acl_setup(unsigned long long* __restrict__ ws) {
    int i = blockIdx.x * 256 + threadIdx.x;
    if (i < NSAMP * NB) ws[i] = 0ull;
    if (blockIdx.x == 0 && threadIdx.x < NB) {
        double* tbl = (double*)(ws + NSAMP * NB);
        int m = threadIdx.x;
        double t = 0.0;
        if (m != 18) {
            double th = (double)(m - 18) * (3.141592653589793 / 18.0);
            t = cos(th) / sin(th);
        }
        tbl[m] = t;
    }
}

__global__ __launch_bounds__(256) void acl_main(const float* __restrict__ mask,
                                                const float* __restrict__ bbox,
                                                unsigned long long* __restrict__ ws) {
    // A_l[r][i]: last pixel of ascending segment i (i=0..17), A_l[r][17]=639.
    // SB_l[r][i] = S(A_l[r][i]) inclusive fixed-point prefix (0 if A=-1).
    __shared__ int A_l[4][18];
    __shared__ unsigned long long SB_l[4][18];
    const int tid = threadIdx.x;
    const int b   = blockIdx.x / 160;
    const int rg  = blockIdx.x % 160;

    const double cxd = (double)bbox[b * 4 + 0] * 640.0;   // exact in f64
    const double cyd = (double)bbox[b * 4 + 1] * 640.0;
    const double* tbl = (const double*)(ws + NSAMP * NB);

    if (tid < 72) {
        SB_l[tid / 18][tid % 18] = 0ull;
        if ((tid % 18) == 17) A_l[tid / 18][17] = W - 1;
    }

    // ---- phase 1: 17 cutpoints per row x 4 rows (validated razor logic) --
    if (tid < 68) {
        const int ri = tid / 17, mi = tid % 17;
        const int y  = rg * 4 + ri;
        const double dy = (double)y - cyd;
        int i, a;
        if (dy == 0.0) {
            // bin 35 for x < cxd, bin 18 for x >= cxd; ceil of EXACT f64 is exact
            i = mi;
            a = (mi == 0) ? ((int)ceil(cxd) - 1) : (W - 1);
        } else {
            const bool dp = (dy > 0.0);
            const int m = dp ? (19 + mi) : (1 + mi);
            double x = cxd + dy * tbl[m];
            x = fmin(fmax(x, -2.0), 642.0);
            double g  = x + 2.0;
            int    gi = (int)g;
            double fr = g - (double)gi;
            int v = dp ? (gi - 2)    // floor(x): max px with bin >= m
                       : (gi - 1);   // ceil(x):  min px with bin >= m
            if (fr < AMB || fr > 1.0 - AMB) {
                int xa = (int)(x + 2.5) - 2;
                if (xa >= 0 && xa <= W - 1) {
                    int kb = bin_slow(xa, y, cxd, cyd);
                    if (dp) v = (kb >= m) ? xa : xa - 1;
                    else    v = (kb >= m) ? xa : xa + 1;
                }
            }
            if (dp) { i = 16 - mi; a = v; }      // ascending: A[i]=T_{35-i}
            else    { i = mi;      a = v - 1; }  // A[i]=U_{i+1}-1
        }
        a = a < -1 ? -1 : (a > W - 1 ? W - 1 : a);
        A_l[ri][i] = a;
    }
    __syncthreads();

    // ---- phase 2: one wave per row; prefix sum, S at cutpoints, 0 atomics -
    const int wid = tid >> 6, lane = tid & 63;
    const int y   = rg * 4 + wid;
    const float4* rp4 = (const float4*)(mask + (size_t)b * (W * H) + (size_t)y * W);

    const int myA = A_l[wid][(lane < 18) ? lane : 0];

    unsigned long long carry = 0ull;
    #pragma unroll
    for (int s = 0; s < 3; s++) {
        const int fi = lane + 64 * s;
        float4 v = make_float4(0.f, 0.f, 0.f, 0.f);
        if (fi < 160) v = rp4[fi];
        const unsigned q0 = __float2uint_rn(v.x * FIX_SCALE);
        const unsigned q1 = __float2uint_rn(v.y * FIX_SCALE);
        const unsigned q2 = __float2uint_rn(v.z * FIX_SCALE);
        const unsigned q3 = __float2uint_rn(v.w * FIX_SCALE);
        const unsigned p0 = q0, p1 = p0 + q1, p2 = p1 + q2, p3 = p2 + q3;

        unsigned incl = p3;                      // 64-lane inclusive scan
        #pragma unroll
        for (int off = 1; off < 64; off <<= 1) {
            unsigned n = __shfl_up(incl, off, 64);
            if (lane >= off) incl += n;
        }
        const unsigned excl = incl - p3;

        // lanes 0..17 fetch S(myA) if myA is in this round's 256-px window
        const bool inr = (myA >= 256 * s) && (myA < 256 * s + 256);
        const int  src = inr ? ((myA - 256 * s) >> 2) : 0;
        const unsigned e_o  = __shfl(excl, src, 64);
        const unsigned p0_o = __shfl(p0, src, 64);
        const unsigned p1_o = __shfl(p1, src, 64);
        const unsigned p2_o = __shfl(p2, src, 64);
        const unsigned p3_o = __shfl(p3, src, 64);
        if (lane < 18 && inr) {
            const int j = myA & 3;
            const unsigned pj = (j == 0) ? p0_o : (j == 1) ? p1_o
                              : (j == 2) ? p2_o : p3_o;
            SB_l[wid][lane] = carry + (unsigned long long)(e_o + pj);
        }
        carry += (unsigned long long)__shfl(incl, 63, 64);
    }
    __syncthreads();

    // ---- finalize: (row, segment) -> pure differences, global atomics ----
    if (tid < 72) {
        const int r = tid / 18, i = tid % 18;
        const int aR = A_l[r][i];
        const int aL = (i == 0) ? -1 : A_l[r][i - 1];
        const int cnt = aR - aL;
        if (cnt > 0) {
            const unsigned long long sR = SB_l[r][i];
            const unsigned long long sL = (i == 0) ? 0ull : SB_l[r][i - 1];
            const double dyr = (double)(rg * 4 + r) - cyd;
            const int bin = (dyr > 0.0) ? (35 - i)
                          : (dyr < 0.0) ? i
                          : (i == 0 ? 35 : 18);
            atomicAdd(&ws[b * NB + bin],
                      ((unsigned long long)cnt << CNT_SHIFT) + (sR - sL));
        }
    }
}

__global__ void acl_final(const unsigned long long* __restrict__ ws,
                          float* __restrict__ out) {
    __shared__ float s[NSAMP];
    const int b = threadIdx.x;   // one thread per sample, block = 64
    int nunder = 0;
    for (int k = 0; k < NB; k++) {
        const unsigned long long v = ws[b * NB + k];
        const unsigned long long cnt = v >> CNT_SHIFT;
        const float sum = (float)(v & ((1ull << CNT_SHIFT) - 1)) * INV_FIX;
        const float act = (cnt != 0ull) ? (sum / (float)cnt) : 0.0f;
        if (act < 0.1f) nunder++;
    }
    s[b] = (float)nunder / 36.0f;
    __syncthreads();
    if (b == 0) {
        float acc = 0.0f;
        for (int i = 0; i < NSAMP; i++) acc += s[i];
        out[0] = acc / 64.0f;   // PENALTY_WEIGHT == 1, float32 output
    }
}

extern "C" void kernel_launch(void* const* d_in, const int* in_sizes, int n_in,
                              void* d_out, int out_size, void* d_ws, size_t ws_size,
                              hipStream_t stream) {
    const float* mask = (const float*)d_in[0];
    const float* bbox = (const float*)d_in[1];
    unsigned long long* ws = (unsigned long long*)d_ws;

    acl_setup<<<dim3((NSAMP * NB + 255) / 256), dim3(256), 0, stream>>>(ws);
    acl_main<<<dim3(NSAMP * 160), dim3(256), 0, stream>>>(mask, bbox, ws);
    acl_final<<<dim3(1), dim3(NSAMP), 0, stream>>>(ws, (float*)d_out);
}

// Round 7
// 72.787 us; speedup vs baseline: 1.0946x; 1.0946x over previous
//
#include <hip/hip_runtime.h>
#include <math.h>

#define NB 36
#define W 640
#define H 640
#define NSAMP 64
#define FIX_SCALE 4194304.0f        // 2^22: full-row sum 640*2^22 < 2^32 (u32-safe)
#define INV_FIX (1.0f/4194304.0f)
#define CNT_SHIFT 44                // sample-bin sum < 640*640*2^22 = 2^40.7 < 2^44
#define AMB 1e-6

// Exact f64 golden chain (validated: absmax==0 in rounds 3-6).
__device__ __forceinline__ int bin_slow(int x, int y, double cxd, double cyd) {
    const double PI_D    = 3.141592653589793;
    const double TWOPI_D = 6.283185307179586;
    double t  = (atan2((double)y - cyd, (double)x - cxd) + PI_D) / TWOPI_D;
    double bd = t * 36.0;
    int k = (int)bd;
    k = k < 0 ? 0 : k;
    return k > NB - 1 ? NB - 1 : k;
}

// zero histogram + build cot table: tbl[m] = cot((m-18)*pi/18)
__global__ void acl_setup(unsigned long long* __restrict__ ws) {
    int i = blockIdx.x * 256 + threadIdx.x;
    if (i < NSAMP * NB) ws[i] = 0ull;
    if (blockIdx.x == 0 && threadIdx.x < NB) {
        double* tbl = (double*)(ws + NSAMP * NB);
        int m = threadIdx.x;
        double t = 0.0;
        if (m != 18) {
            double th = (double)(m - 18) * (3.141592653589793 / 18.0);
            t = cos(th) / sin(th);
        }
        tbl[m] = t;
    }
}

// one DPP scan step: x += shifted(x) (invalid source lanes contribute 0)
#define SCAN_STEP(x, ctrl, rmask)                                             \
    x += (unsigned)__builtin_amdgcn_update_dpp(0, (int)(x), (ctrl), (rmask),  \
                                               0xf, false)

__global__ __launch_bounds__(256) void acl_main(const float* __restrict__ mask,
                                                const float* __restrict__ bbox,
                                                unsigned long long* __restrict__ ws) {
    __shared__ int A_l[4][18];                 // segment right-ends (ascending)
    __shared__ unsigned SB_l[4][18];           // row prefix S(A) at cutpoints
    __shared__ __align__(16) unsigned srow[4][768];  // global-inclusive row prefixes
    const int tid = threadIdx.x;
    const int b   = blockIdx.x / 160;
    const int rg  = blockIdx.x % 160;

    const double cxd = (double)bbox[b * 4 + 0] * 640.0;   // exact in f64
    const double cyd = (double)bbox[b * 4 + 1] * 640.0;
    const double* tbl = (const double*)(ws + NSAMP * NB);

    if (tid < 72 && (tid % 18) == 17) A_l[tid / 18][17] = W - 1;

    // ---- phase 1: 17 cutpoints per row x 4 rows (validated razor logic) --
    if (tid < 68) {
        const int ri = tid / 17, mi = tid % 17;
        const int y  = rg * 4 + ri;
        const double dy = (double)y - cyd;
        int i, a;
        if (dy == 0.0) {
            i = mi;
            a = (mi == 0) ? ((int)ceil(cxd) - 1) : (W - 1);
        } else {
            const bool dp = (dy > 0.0);
            const int m = dp ? (19 + mi) : (1 + mi);
            double x = cxd + dy * tbl[m];
            x = fmin(fmax(x, -2.0), 642.0);
            double g  = x + 2.0;
            int    gi = (int)g;
            double fr = g - (double)gi;
            int v = dp ? (gi - 2)    // floor(x): max px with bin >= m
                       : (gi - 1);   // ceil(x):  min px with bin >= m
            if (fr < AMB || fr > 1.0 - AMB) {
                int xa = (int)(x + 2.5) - 2;
                if (xa >= 0 && xa <= W - 1) {
                    int kb = bin_slow(xa, y, cxd, cyd);
                    if (dp) v = (kb >= m) ? xa : xa - 1;
                    else    v = (kb >= m) ? xa : xa + 1;
                }
            }
            if (dp) { i = 16 - mi; a = v; }      // ascending: A[i]=T_{35-i}
            else    { i = mi;      a = v - 1; }  // A[i]=U_{i+1}-1
        }
        a = a < -1 ? -1 : (a > W - 1 ? W - 1 : a);
        A_l[ri][i] = a;
    }
    __syncthreads();

    // ---- phase 2: one wave per row; DPP scan, LDS row image, 1 lookup ----
    const int wid = tid >> 6, lane = tid & 63;
    const int y   = rg * 4 + wid;
    const float4* rp4 = (const float4*)(mask + (size_t)b * (W * H) + (size_t)y * W);

    const int myA = A_l[wid][(lane < 18) ? lane : 0];

    unsigned carry = 0u;
    #pragma unroll
    for (int s = 0; s < 3; s++) {
        const int fi = lane + 64 * s;
        float4 v = make_float4(0.f, 0.f, 0.f, 0.f);
        if (fi < 160) v = rp4[fi];
        const unsigned q0 = __float2uint_rn(v.x * FIX_SCALE);
        const unsigned q1 = __float2uint_rn(v.y * FIX_SCALE);
        const unsigned q2 = __float2uint_rn(v.z * FIX_SCALE);
        const unsigned q3 = __float2uint_rn(v.w * FIX_SCALE);
        const unsigned p0 = q0, p1 = p0 + q1, p2 = p1 + q2, p3 = p2 + q3;

        unsigned x = p3;                 // 64-lane inclusive scan, pure VALU
        SCAN_STEP(x, 0x111, 0xf);        // row_shr:1
        SCAN_STEP(x, 0x112, 0xf);        // row_shr:2
        SCAN_STEP(x, 0x114, 0xf);        // row_shr:4
        SCAN_STEP(x, 0x118, 0xf);        // row_shr:8
        SCAN_STEP(x, 0x142, 0xa);        // row_bcast:15 -> rows 1,3
        SCAN_STEP(x, 0x143, 0xc);        // row_bcast:31 -> rows 2,3

        const unsigned base = carry + (x - p3);   // global exclusive prefix
        uint4 wv;
        wv.x = base + p0; wv.y = base + p1; wv.z = base + p2; wv.w = base + p3;
        *((uint4*)&srow[wid][s * 256 + lane * 4]) = wv;   // ds_write_b128

        carry += (unsigned)__builtin_amdgcn_readlane((int)x, 63);
    }

    if (lane < 18)
        SB_l[wid][lane] = (myA >= 0) ? srow[wid][myA] : 0u;   // one ds_read_b32
    __syncthreads();

    // ---- finalize: (row, segment) -> pure differences, global atomics ----
    if (tid < 72) {
        const int r = tid / 18, i = tid % 18;
        const int aR = A_l[r][i];
        const int aL = (i == 0) ? -1 : A_l[r][i - 1];
        const int cnt = aR - aL;
        if (cnt > 0) {
            const unsigned sR = SB_l[r][i];
            const unsigned sL = (i == 0) ? 0u : SB_l[r][i - 1];
            const double dyr = (double)(rg * 4 + r) - cyd;
            const int bin = (dyr > 0.0) ? (35 - i)
                          : (dyr < 0.0) ? i
                          : (i == 0 ? 35 : 18);
            atomicAdd(&ws[b * NB + bin],
                      ((unsigned long long)cnt << CNT_SHIFT)
                      + (unsigned long long)(sR - sL));
        }
    }
}

__global__ void acl_final(const unsigned long long* __restrict__ ws,
                          float* __restrict__ out) {
    __shared__ float s[NSAMP];
    const int b = threadIdx.x;   // one thread per sample, block = 64
    int nunder = 0;
    for (int k = 0; k < NB; k++) {
        const unsigned long long v = ws[b * NB + k];
        const unsigned long long cnt = v >> CNT_SHIFT;
        const float sum = (float)(v & ((1ull << CNT_SHIFT) - 1)) * INV_FIX;
        const float act = (cnt != 0ull) ? (sum / (float)cnt) : 0.0f;
        if (act < 0.1f) nunder++;
    }
    s[b] = (float)nunder / 36.0f;
    __syncthreads();
    if (b == 0) {
        float acc = 0.0f;
        for (int i = 0; i < NSAMP; i++) acc += s[i];
        out[0] = acc / 64.0f;   // PENALTY_WEIGHT == 1, float32 output
    }
}

extern "C" void kernel_launch(void* const* d_in, const int* in_sizes, int n_in,
                              void* d_out, int out_size, void* d_ws, size_t ws_size,
                              hipStream_t stream) {
    const float* mask = (const float*)d_in[0];
    const float* bbox = (const float*)d_in[1];
    unsigned long long* ws = (unsigned long long*)d_ws;

    acl_setup<<<dim3((NSAMP * NB + 255) / 256), dim3(256), 0, stream>>>(ws);
    acl_main<<<dim3(NSAMP * 160), dim3(256), 0, stream>>>(mask, bbox, ws);
    acl_final<<<dim3(1), dim3(NSAMP), 0, stream>>>(ws, (float*)d_out);
}

// Round 8
// 35.871 us; speedup vs baseline: 2.2212x; 2.0291x over previous
//
#include <hip/hip_runtime.h>
#include <math.h>

#define NB 36
#define W 640
#define H 640
#define NSAMP 64
#define RPB 40                     // rows per block
#define BPS 16                     // blocks per sample (16*40 = 640)
#define FIX_SCALE 4194304.0f       // 2^22: row prefix < 640*2^22 < 2^32
#define INV_FIX (1.0f/4194304.0f)
#define CNT_SHIFT 44               // sample-bin sum < 2^40.7 < 2^44
#define AMB 1e-6

// Exact f64 golden chain (validated: absmax==0 in rounds 3-7).
__device__ __forceinline__ int bin_slow(int x, int y, double cxd, double cyd) {
    const double PI_D    = 3.141592653589793;
    const double TWOPI_D = 6.283185307179586;
    double t  = (atan2((double)y - cyd, (double)x - cxd) + PI_D) / TWOPI_D;
    double bd = t * 36.0;
    int k = (int)bd;
    k = k < 0 ? 0 : k;
    return k > NB - 1 ? NB - 1 : k;
}

// zero histogram + build cot table: tbl[m] = cot((m-18)*pi/18)
__global__ void acl_setup(unsigned long long* __restrict__ ws) {
    int i = blockIdx.x * 256 + threadIdx.x;
    if (i < NSAMP * NB) ws[i] = 0ull;
    if (blockIdx.x == 0 && threadIdx.x < NB) {
        double* tbl = (double*)(ws + NSAMP * NB);
        int m = threadIdx.x;
        double t = 0.0;
        if (m != 18) {
            double th = (double)(m - 18) * (3.141592653589793 / 18.0);
            t = cos(th) / sin(th);
        }
        tbl[m] = t;
    }
}

// one DPP scan step: x += shifted(x)  (validated round 7)
#define SCAN_STEP(x, ctrl, rmask)                                             \
    x += (unsigned)__builtin_amdgcn_update_dpp(0, (int)(x), (ctrl), (rmask),  \
                                               0xf, false)

__global__ __launch_bounds__(256) void acl_main(const float* __restrict__ mask,
                                                const float* __restrict__ bbox,
                                                unsigned long long* __restrict__ ws) {
    __shared__ int A_l[RPB][18];               // ascending segment right-ends
    __shared__ int sgn_l[RPB];                 // sign(dy) per row
    __shared__ __align__(16) unsigned srow[4][2][768];  // per-wave prefix image
    __shared__ unsigned long long lbin[NB];

    const int tid = threadIdx.x;
    const int b   = blockIdx.x >> 4;           // sample
    const int rg  = blockIdx.x & (BPS - 1);    // 40-row group
    const int y0  = rg * RPB;

    if (tid < NB) lbin[tid] = 0ull;
    if (tid < RPB) A_l[tid][17] = W - 1;       // sentinel

    const double cxd = (double)bbox[b * 4 + 0] * 640.0;   // exact in f64
    const double cyd = (double)bbox[b * 4 + 1] * 640.0;
    const double* tbl = (const double*)(ws + NSAMP * NB);

    // ---- phase 1: 40 rows x 17 cutpoints (validated razor logic) ---------
    for (int task = tid; task < RPB * 17; task += 256) {
        const int rl = task / 17, mi = task % 17;
        const int y  = y0 + rl;
        const double dy = (double)y - cyd;
        int i, a;
        if (dy == 0.0) {
            if (mi == 0) sgn_l[rl] = 0;
            i = mi;
            a = (mi == 0) ? ((int)ceil(cxd) - 1) : (W - 1);
        } else {
            const bool dp = (dy > 0.0);
            if (mi == 0) sgn_l[rl] = dp ? 1 : -1;
            const int m = dp ? (19 + mi) : (1 + mi);
            double x = cxd + dy * tbl[m];
            x = fmin(fmax(x, -2.0), 642.0);
            double g  = x + 2.0;
            int    gi = (int)g;
            double fr = g - (double)gi;
            int v = dp ? (gi - 2)    // floor(x): max px with bin >= m
                       : (gi - 1);   // ceil(x):  min px with bin >= m
            if (fr < AMB || fr > 1.0 - AMB) {
                int xa = (int)(x + 2.5) - 2;
                if (xa >= 0 && xa <= W - 1) {
                    int kb = bin_slow(xa, y, cxd, cyd);
                    if (dp) v = (kb >= m) ? xa : xa - 1;
                    else    v = (kb >= m) ? xa : xa + 1;
                }
            }
            if (dp) { i = 16 - mi; a = v; }      // ascending index
            else    { i = mi;      a = v - 1; }
        }
        a = a < -1 ? -1 : (a > W - 1 ? W - 1 : a);
        A_l[rl][i] = a;
    }
    __syncthreads();

    // ---- phase 2: each wave streams 10 rows, 1-row prefetch, no barriers -
    const int wid = tid >> 6, lane = tid & 63;
    const float* rowbase = mask + (size_t)b * (W * H) + (size_t)y0 * W;

    unsigned long long accPs = 0ull, accNs = 0ull;
    unsigned accPc = 0u, accNc = 0u;

    const float4* rp = (const float4*)(rowbase + (size_t)wid * W);
    float4 c0 = rp[lane];
    float4 c1 = rp[lane + 64];
    float4 c2 = (lane < 32) ? rp[lane + 128] : make_float4(0.f, 0.f, 0.f, 0.f);

    for (int j = 0; j < 10; j++) {
        const int rl = wid + 4 * j;
        float4 n0, n1, n2;
        if (j < 9) {                           // prefetch next row
            const float4* np = (const float4*)(rowbase + (size_t)(rl + 4) * W);
            n0 = np[lane];
            n1 = np[lane + 64];
            n2 = (lane < 32) ? np[lane + 128] : make_float4(0.f, 0.f, 0.f, 0.f);
        }

        const int buf = j & 1;
        unsigned carry = 0u;
        #pragma unroll
        for (int s = 0; s < 3; s++) {
            const float4 v = (s == 0) ? c0 : (s == 1) ? c1 : c2;
            const unsigned q0 = __float2uint_rn(v.x * FIX_SCALE);
            const unsigned q1 = __float2uint_rn(v.y * FIX_SCALE);
            const unsigned q2 = __float2uint_rn(v.z * FIX_SCALE);
            const unsigned q3 = __float2uint_rn(v.w * FIX_SCALE);
            const unsigned p0 = q0, p1 = p0 + q1, p2 = p1 + q2, p3 = p2 + q3;

            unsigned x = p3;                   // 64-lane inclusive scan (VALU)
            SCAN_STEP(x, 0x111, 0xf);          // row_shr:1
            SCAN_STEP(x, 0x112, 0xf);          // row_shr:2
            SCAN_STEP(x, 0x114, 0xf);          // row_shr:4
            SCAN_STEP(x, 0x118, 0xf);          // row_shr:8
            SCAN_STEP(x, 0x142, 0xa);          // row_bcast:15
            SCAN_STEP(x, 0x143, 0xc);          // row_bcast:31
            const unsigned base = carry + (x - p3);
            uint4 wv;
            wv.x = base + p0; wv.y = base + p1; wv.z = base + p2; wv.w = base + p3;
            *((uint4*)&srow[wid][buf][s * 256 + lane * 4]) = wv;
            carry += (unsigned)__builtin_amdgcn_readlane((int)x, 63);
        }

        if (lane < 18) {                       // wave-private segment extract
            const int aR = A_l[rl][lane];
            const int aL = (lane == 0) ? -1 : A_l[rl][lane - 1];
            const int cnt = aR - aL;
            if (cnt > 0) {                     // cnt>0 => aR >= 0
                const unsigned sR = srow[wid][buf][aR];
                const unsigned sL = (aL >= 0) ? srow[wid][buf][aL] : 0u;
                const unsigned seg = sR - sL;
                const int sg = sgn_l[rl];
                if (sg > 0)      { accPc += (unsigned)cnt; accPs += seg; }
                else if (sg < 0) { accNc += (unsigned)cnt; accNs += seg; }
                else atomicAdd(&lbin[(lane == 0) ? 35 : 18],
                               ((unsigned long long)cnt << CNT_SHIFT)
                               + (unsigned long long)seg);
            }
        }
        if (j < 9) { c0 = n0; c1 = n1; c2 = n2; }
    }

    // ---- flush: registers -> LDS (<=36 lane-atomics/wave) -> global ------
    if (lane < 18) {
        if (accPc) atomicAdd(&lbin[35 - lane],
                             ((unsigned long long)accPc << CNT_SHIFT) + accPs);
        if (accNc) atomicAdd(&lbin[lane],
                             ((unsigned long long)accNc << CNT_SHIFT) + accNs);
    }
    __syncthreads();
    if (tid < NB) {
        const unsigned long long v = lbin[tid];
        if (v) atomicAdd(&ws[b * NB + tid], v);
    }
}

__global__ __launch_bounds__(256) void acl_final(const unsigned long long* __restrict__ ws,
                                                 float* __restrict__ out) {
    __shared__ unsigned long long h[NSAMP * NB];
    __shared__ float s[NSAMP];
    const int tid = threadIdx.x;
    for (int i = tid; i < NSAMP * NB; i += 256) h[i] = ws[i];  // coalesced
    __syncthreads();
    if (tid < NSAMP) {
        int nunder = 0;
        for (int k = 0; k < NB; k++) {
            const unsigned long long v = h[tid * NB + k];
            const unsigned long long cnt = v >> CNT_SHIFT;
            const float sum = (float)(v & ((1ull << CNT_SHIFT) - 1)) * INV_FIX;
            const float act = (cnt != 0ull) ? (sum / (float)cnt) : 0.0f;
            if (act < 0.1f) nunder++;
        }
        s[tid] = (float)nunder / 36.0f;
    }
    __syncthreads();
    if (tid == 0) {
        float acc = 0.0f;
        for (int i = 0; i < NSAMP; i++) acc += s[i];
        out[0] = acc / 64.0f;   // PENALTY_WEIGHT == 1, float32 output
    }
}

extern "C" void kernel_launch(void* const* d_in, const int* in_sizes, int n_in,
                              void* d_out, int out_size, void* d_ws, size_t ws_size,
                              hipStream_t stream) {
    const float* mask = (const float*)d_in[0];
    const float* bbox = (const float*)d_in[1];
    unsigned long long* ws = (unsigned long long*)d_ws;

    acl_setup<<<dim3((NSAMP * NB + 255) / 256), dim3(256), 0, stream>>>(ws);
    acl_main<<<dim3(NSAMP * BPS), dim3(256), 0, stream>>>(mask, bbox, ws);
    acl_final<<<dim3(1), dim3(256), 0, stream>>>(ws, (float*)d_out);
}